// Round 16
// baseline (237.918 us; speedup 1.0000x reference)
//
#include <hip/hip_runtime.h>
#include <cstdint>
#include <cstddef>

#define NV 5
#define NC 128
#define NT 128
#define NB 128
typedef unsigned long long ull;
typedef float f32x2 __attribute__((ext_vector_type(2)));
typedef float f32x4 __attribute__((ext_vector_type(4)));

__device__ __forceinline__ float fa(float a, float b){ return __fadd_rn(a,b); }
__device__ __forceinline__ float fm(float a, float b){ return __fmul_rn(a,b); }
__device__ __forceinline__ float fs(float a, float b){ return __fsub_rn(a,b); }

// packed fp32: two independent IEEE-RNE ops per instruction (bit-identical
// to v_mul_f32/v_add_f32 per half)
__device__ __forceinline__ f32x2 pkmul(f32x2 a, f32x2 b){
    f32x2 d; asm("v_pk_mul_f32 %0, %1, %2" : "=v"(d) : "v"(a), "v"(b)); return d;
}
__device__ __forceinline__ f32x2 pkadd(f32x2 a, f32x2 b){
    f32x2 d; asm("v_pk_add_f32 %0, %1, %2" : "=v"(d) : "v"(a), "v"(b)); return d;
}

// numpy pairwise_sum base case, n=80, contiguous fp32
__device__ __forceinline__ float base80(const float* a)
{
    float r0=a[0],r1=a[1],r2=a[2],r3=a[3],r4=a[4],r5=a[5],r6=a[6],r7=a[7];
    #pragma unroll
    for (int i = 8; i < 80; i += 8) {
        r0=fa(r0,a[i+0]); r1=fa(r1,a[i+1]); r2=fa(r2,a[i+2]); r3=fa(r3,a[i+3]);
        r4=fa(r4,a[i+4]); r5=fa(r5,a[i+5]); r6=fa(r6,a[i+6]); r7=fa(r7,a[i+7]);
    }
    return fa(fa(fa(r0,r1),fa(r2,r3)), fa(fa(r4,r5),fa(r6,r7)));
}

// base80 over (a[i]-mu)^2, identical op order to the var phase
__device__ __forceinline__ float base80v(const float* a, float mu)
{
    float r[8];
    #pragma unroll
    for (int j = 0; j < 8; ++j) { const float d = fs(a[j], mu); r[j] = fm(d, d); }
    #pragma unroll
    for (int i = 8; i < 80; i += 8)
        #pragma unroll
        for (int j = 0; j < 8; ++j) {
            const float d = fs(a[i + j], mu);
            r[j] = fa(r[j], fm(d, d));
        }
    return fa(fa(fa(r[0],r[1]),fa(r[2],r[3])), fa(fa(r[4],r[5]),fa(r[6],r[7])));
}

// =========================================================================
// Kernel T: W[o][c] -> Wt[fc][o]  (exact copy; enables coalesced kA reads)
// =========================================================================
__global__ __launch_bounds__(256) void kT(const float* __restrict__ W,
                                          float* __restrict__ Wt)
{
    const int i = blockIdx.x * 256 + threadIdx.x;   // 0..32767 = fc*128+o
    const int fc = i >> 7, o = i & 127;
    Wt[i] = W[o * 256 + fc];
}

// =========================================================================
// Kernel A: np-mimic fp32 fusion matmul + GN1, two-phase K-staging.
// 128 threads = 2 waves; wave wv owns samples {2wv,2wv+1}; thread owns
// channels {lane, lane+64}. Per phase ph: stage fc in [ph*128, ph*128+128)
// into a 12.3 KB wave-private LDS buffer, then matmul that half (acc
// carried across phases -> fc ascending 0..255, bit-exact chain order).
// No barriers between phases (same-wave DS ordering). 12.3 KB LDS ->
// ~12 blocks/CU for latency hiding. Math identical to the passing kernel.
// =========================================================================
__global__ __launch_bounds__(128) void kA(const float* __restrict__ x,
                                          const float* __restrict__ Wt,
                                          const float* __restrict__ g1w,
                                          const float* __restrict__ g1b,
                                          float* __restrict__ y1)
{
    const int n0   = blockIdx.x * 4;
    const int tid  = threadIdx.x;
    const int lane = tid & 63;
    const int wv   = tid >> 6;             // wave id == sample-pair id

    __shared__ __align__(16) float xs[128 * 2 * 12];   // 12288 B
    __shared__ float statA[4][4];
    __shared__ float muS[4], rstdS[4];

    f32x2 accA[NV], accB[NV];
    #pragma unroll
    for (int v = 0; v < NV; ++v) { accA[v] = (f32x2){0.f,0.f}; accB[v] = (f32x2){0.f,0.f}; }

    const float* xrow = xs + wv * 12;

    #pragma unroll
    for (int ph = 0; ph < 2; ++ph) {
        // ---- stage this fc-half: wave-private region, predicated scatter
        {
            const float4* g0 = (const float4*)(x + (size_t)(n0 + 2 * wv) * 1280);
            const float4* g1 = g0 + 320;
            #pragma unroll
            for (int it = 0; it < 5; ++it) {
                const int k = it * 64 + lane;          // quad index 0..319
                const float4 a = g0[k];
                const float4 b = g1[k];
                const float av[4] = {a.x, a.y, a.z, a.w};
                const float bv[4] = {b.x, b.y, b.z, b.w};
                int f = k * 4;
                #pragma unroll
                for (int e = 0; e < 4; ++e, ++f) {
                    const int c  = f / 10;
                    const int j  = f - c * 10;
                    const int v  = (j < 5) ? j : j - 5;
                    const int fc = (j < 5) ? c : c + 128;
                    if ((fc >> 7) == ph) {
                        f32x2 pr; pr.x = av[e]; pr.y = bv[e];
                        *(f32x2*)&xs[((fc & 127) * 2 + wv) * 12 + v * 2] = pr;
                    }
                }
            }
        }

        // ---- matmul over this half: fc ascending (global order preserved)
        #pragma unroll 2
        for (int fc2 = 0; fc2 < 128; ++fc2) {
            const int fco = ph * 128 + fc2;
            const float wa = Wt[fco * 128 + lane];        // coalesced, L1/L2
            const float wb = Wt[fco * 128 + 64 + lane];
            const f32x4 Q0 = *(const f32x4*)&xrow[fc2 * 24];       // v0,v1
            const f32x4 Q1 = *(const f32x4*)&xrow[fc2 * 24 + 4];   // v2,v3
            const f32x2 P4 = *(const f32x2*)&xrow[fc2 * 24 + 8];   // v4
            f32x2 wpa; wpa.x = wa; wpa.y = wa;
            f32x2 wpb; wpb.x = wb; wpb.y = wb;
            const f32x2 p0 = __builtin_shufflevector(Q0, Q0, 0, 1);
            const f32x2 p1 = __builtin_shufflevector(Q0, Q0, 2, 3);
            const f32x2 p2 = __builtin_shufflevector(Q1, Q1, 0, 1);
            const f32x2 p3 = __builtin_shufflevector(Q1, Q1, 2, 3);
            accA[0] = pkadd(accA[0], pkmul(wpa, p0));
            accA[1] = pkadd(accA[1], pkmul(wpa, p1));
            accA[2] = pkadd(accA[2], pkmul(wpa, p2));
            accA[3] = pkadd(accA[3], pkmul(wpa, p3));
            accA[4] = pkadd(accA[4], pkmul(wpa, P4));
            accB[0] = pkadd(accB[0], pkmul(wpb, p0));
            accB[1] = pkadd(accB[1], pkmul(wpb, p1));
            accB[2] = pkadd(accB[2], pkmul(wpb, p2));
            accB[3] = pkadd(accB[3], pkmul(wpb, p3));
            accB[4] = pkadd(accB[4], pkmul(wpb, P4));
        }
    }
    __syncthreads();   // other wave may still read xs; wait before ys reuse

    float* ys = xs;    // [4][640] stats buffer? 2560 floats > 3072 avail ✓

    #pragma unroll
    for (int sl = 0; sl < 2; ++sl) {
        const int g = wv * 2 + sl;
        #pragma unroll
        for (int v = 0; v < NV; ++v) {
            ys[g * 640 + lane * 5 + v]        = sl ? accA[v].y : accA[v].x;
            ys[g * 640 + (lane + 64) * 5 + v] = sl ? accB[v].y : accB[v].x;
        }
    }
    __syncthreads();

    // mean: numpy pairwise over 640 (o-major order)
    if (tid < 16) {
        const int g = tid >> 2, p = tid & 3;
        const float b0 = base80(&ys[g * 640 + (2 * p) * 80]);
        const float b1 = base80(&ys[g * 640 + (2 * p + 1) * 80]);
        statA[g][p] = fa(b0, b1);
    }
    __syncthreads();
    if (tid < 4) {
        const int g = tid;
        const float tot = fa(fa(statA[g][0], statA[g][1]), fa(statA[g][2], statA[g][3]));
        muS[g] = __fdiv_rn(tot, 640.f);
    }
    __syncthreads();

    // var: overwrite ys with (a - mu)^2, pairwise / 640
    #pragma unroll
    for (int sl = 0; sl < 2; ++sl) {
        const int g = wv * 2 + sl;
        const float mu = muS[g];
        #pragma unroll
        for (int v = 0; v < NV; ++v) {
            const float aA = sl ? accA[v].y : accA[v].x;
            const float aB = sl ? accB[v].y : accB[v].x;
            const float dA = fs(aA, mu);
            const float dB = fs(aB, mu);
            ys[g * 640 + lane * 5 + v]        = fm(dA, dA);
            ys[g * 640 + (lane + 64) * 5 + v] = fm(dB, dB);
        }
    }
    __syncthreads();
    if (tid < 16) {
        const int g = tid >> 2, p = tid & 3;
        const float b0 = base80(&ys[g * 640 + (2 * p) * 80]);
        const float b1 = base80(&ys[g * 640 + (2 * p + 1) * 80]);
        statA[g][p] = fa(b0, b1);
    }
    __syncthreads();
    if (tid < 4) {
        const int g = tid;
        const float tot = fa(fa(statA[g][0], statA[g][1]), fa(statA[g][2], statA[g][3]));
        const float var = __fdiv_rn(tot, 640.f);
        rstdS[g] = __fdiv_rn(1.f, __fsqrt_rn(fa(var, 1e-5f)));
    }
    __syncthreads();

    #pragma unroll
    for (int ch = 0; ch < 2; ++ch) {
        const int o = lane + ch * 64;
        const float wf = g1w[o], bf = g1b[o];
        #pragma unroll
        for (int sl = 0; sl < 2; ++sl) {
            const int g = wv * 2 + sl;
            const float mu = muS[g], rstd = rstdS[g];
            const int n = n0 + g;
            #pragma unroll
            for (int v = 0; v < NV; ++v) {
                const float av = ch ? (sl ? accB[v].y : accB[v].x)
                                    : (sl ? accA[v].y : accA[v].x);
                const float xn = fm(fs(av, mu), rstd);
                y1[(size_t)n * 640 + o * 5 + v] = fa(fm(xn, wf), bf);
            }
        }
    }
}

// =========================================================================
// Kernel B1: LIF1 (fp32, identical chain) -> ulonglong2 spike masks.
// =========================================================================
__global__ __launch_bounds__(320) void kB1(const float* __restrict__ y1,
                                           ulonglong2* __restrict__ masks)
{
    const int b   = blockIdx.x >> 1;
    const int c0  = (blockIdx.x & 1) * 64;
    const int tid = threadIdx.x;           // 0..319

    ull lo = 0ull, hi = 0ull;
    float vm = 0.f;
    const float* p = y1 + (size_t)b * 640 + (size_t)c0 * 5 + tid;
    for (int t0 = 0; t0 < NT; t0 += 16) {
        float xv[16];
        #pragma unroll
        for (int j = 0; j < 16; ++j)
            xv[j] = p[(size_t)(t0 + j) * (NB * 640)];
        #pragma unroll
        for (int j = 0; j < 16; ++j) {
            vm = fa(vm, fm(fs(xv[j], vm), 0.5f));
            if (vm >= 0.8f) {
                const int t = t0 + j;
                if (t < 64) lo |= 1ull << t; else hi |= 1ull << (t - 64);
                vm = 0.f;
            }
        }
    }
    masks[(size_t)b * 640 + (size_t)c0 * 5 + tid] = make_ulonglong2(lo, hi);
}

// =========================================================================
// Kernel B2: conv once (LDS) -> pairwise GN2 -> LIF2 -> coalesced stores.
// =========================================================================
__device__ __forceinline__ float bitf(ull lo, ull hi, int t)
{
    if (t < 0 || t > 127) return 0.f;
    return (float)(((t < 64) ? (lo >> t) : (hi >> (t - 64))) & 1ull);
}

__global__ __launch_bounds__(512) void kB2(const ulonglong2* __restrict__ masks,
                                           const float* __restrict__ Wm,
                                           const float* __restrict__ g2w,
                                           const float* __restrict__ g2b,
                                           const float* __restrict__ adj,
                                           float* __restrict__ out)
{
    const int blk = blockIdx.x;            // 0..4095
    const int b   = blk >> 5;              // 0..127
    const int c0  = (blk & 31) * 4;        // 0,4,..,124
    const int tid = threadIdx.x;           // 0..511
    const int p   = tid >> 7;              // pair 0..3
    const int lt  = tid & 127;             // t index / worker id

    __shared__ float mw_s[75];
    __shared__ ull   m_lo[4][5], m_hi[4][5];
    __shared__ float conv_s[4][5][128];
    __shared__ float spk_s[128][40];
    __shared__ float stat_s[4][8];
    __shared__ float mu_s[4], rstd_s[4];

    if (tid < 75) {
        const int oo = tid / 15, rem = tid % 15, ii = rem / 3;
        const float sym = fm(0.5f, fa(adj[oo * 5 + ii], adj[ii * 5 + oo]));
        const float e = (float)exp(-(double)sym);
        const float sig = __fdiv_rn(1.f, fa(1.f, e));
        mw_s[tid] = fm(Wm[tid], sig);
    }
    if (tid < 20) {
        const int pp = tid / 5, vv = tid % 5;
        const ulonglong2 m = masks[((size_t)b * 128 + c0 + pp) * 5 + vv];
        m_lo[pp][vv] = m.x; m_hi[pp][vv] = m.y;
    }
    __syncthreads();

    // ---- conv once: thread (p, t=lt); 15 shared bit extracts, 5 nodes
    {
        float bv[5][3];
        #pragma unroll
        for (int i = 0; i < 5; ++i) {
            const ull lo = m_lo[p][i], hi = m_hi[p][i];
            #pragma unroll
            for (int k = 0; k < 3; ++k)
                bv[i][k] = bitf(lo, hi, lt - 1 + k);
        }
        #pragma unroll
        for (int o = 0; o < 5; ++o) {
            float res = 0.f;
            #pragma unroll
            for (int i = 0; i < 5; ++i)
                #pragma unroll
                for (int k = 0; k < 3; ++k)
                    res = fa(res, fm(mw_s[(o * 5 + i) * 3 + k], bv[i][k]));
            conv_s[p][o][lt] = res;
        }
    }
    __syncthreads();

    // ---- GN2 mean
    if (lt < 8)
        stat_s[p][lt] = base80(&conv_s[p][0][0] + lt * 80);
    __syncthreads();
    if (lt == 0) {
        const float* s = stat_s[p];
        const float tot = fa(fa(fa(s[0],s[1]),fa(s[2],s[3])),
                             fa(fa(s[4],s[5]),fa(s[6],s[7])));
        mu_s[p] = __fdiv_rn(tot, 640.f);
    }
    __syncthreads();

    // ---- GN2 var
    if (lt < 8)
        stat_s[p][lt] = base80v(&conv_s[p][0][0] + lt * 80, mu_s[p]);
    __syncthreads();
    if (lt == 0) {
        const float* s = stat_s[p];
        const float tot = fa(fa(fa(s[0],s[1]),fa(s[2],s[3])),
                             fa(fa(s[4],s[5]),fa(s[6],s[7])));
        const float var = __fdiv_rn(tot, 640.f);
        rstd_s[p] = __fdiv_rn(1.f, __fsqrt_rn(fa(var, 1e-5f)));
    }
    __syncthreads();

    // ---- LIF2: 5 threads per pair (o = lt), spikes -> LDS
    if (lt < 5) {
        const int o = lt;
        const float mu = mu_s[p], rstd = rstd_s[p];
        const float gw = g2w[o], gb = g2b[o];
        float vm = 0.f;
        for (int t = 0; t < NT; ++t) {
            const float z  = conv_s[p][o][t];
            const float xn = fm(fs(z, mu), rstd);
            const float yn = fa(fm(xn, gw), gb);
            vm = fa(vm, fm(fs(yn, vm), 0.5f));
            const bool sp = (vm >= 0.8f);
            if (sp) vm = 0.f;
            const float so = sp ? 1.f : 0.f;
            spk_s[t][p * 10 + o]     = so;
            spk_s[t][p * 10 + 5 + o] = so;
        }
    }
    __syncthreads();

    // ---- coalesced store
    for (int q = tid; q < 1280; q += 512) {
        const int t = q / 10, s = q - t * 10;
        float4* dst = (float4*)(out + ((size_t)(t * NB + b) * 1280 + c0 * 10));
        dst[s] = reinterpret_cast<const float4*>(&spk_s[t][0])[s];
    }
}

// =========================================================================
extern "C" void kernel_launch(void* const* d_in, const int* in_sizes, int n_in,
                              void* d_out, int out_size, void* d_ws, size_t ws_size,
                              hipStream_t stream)
{
    const float* x   = (const float*)d_in[0];
    const float* W   = (const float*)d_in[1];
    const float* g1w = (const float*)d_in[2];
    const float* g1b = (const float*)d_in[3];
    const float* Wm  = (const float*)d_in[4];
    const float* g2w = (const float*)d_in[5];
    const float* g2b = (const float*)d_in[6];
    const float* adj = (const float*)d_in[7];
    float* out = (float*)d_out;

    float* y1 = (float*)d_ws;                                     // 41.9 MB
    ulonglong2* masks = (ulonglong2*)((char*)d_ws + (64u << 20)); // 1.3 MB
    float* Wt = (float*)((char*)d_ws + (80u << 20));              // 128 KB

    hipLaunchKernelGGL(kT, dim3(128), dim3(256), 0, stream, W, Wt);
    hipLaunchKernelGGL(kA, dim3(NT * NB / 4), dim3(128), 0, stream,
                       x, Wt, g1w, g1b, y1);
    hipLaunchKernelGGL(kB1, dim3(NB * 2), dim3(320), 0, stream,
                       y1, masks);
    hipLaunchKernelGGL(kB2, dim3(4096), dim3(512), 0, stream,
                       masks, Wm, g2w, g2b, adj, out);
}

// Round 17
// 237.836 us; speedup vs baseline: 1.0003x; 1.0003x over previous
//
#include <hip/hip_runtime.h>
#include <cstdint>
#include <cstddef>

#define NV 5
#define NC 128
#define NT 128
#define NB 128
typedef unsigned long long ull;
typedef float f32x2 __attribute__((ext_vector_type(2)));
typedef float f32x4 __attribute__((ext_vector_type(4)));

__device__ __forceinline__ float fa(float a, float b){ return __fadd_rn(a,b); }
__device__ __forceinline__ float fm(float a, float b){ return __fmul_rn(a,b); }
__device__ __forceinline__ float fs(float a, float b){ return __fsub_rn(a,b); }

// packed fp32: two independent IEEE-RNE ops per instruction (bit-identical
// to v_mul_f32/v_add_f32 per half)
__device__ __forceinline__ f32x2 pkmul(f32x2 a, f32x2 b){
    f32x2 d; asm("v_pk_mul_f32 %0, %1, %2" : "=v"(d) : "v"(a), "v"(b)); return d;
}
__device__ __forceinline__ f32x2 pkadd(f32x2 a, f32x2 b){
    f32x2 d; asm("v_pk_add_f32 %0, %1, %2" : "=v"(d) : "v"(a), "v"(b)); return d;
}

// numpy pairwise_sum base case, n=80, contiguous fp32
__device__ __forceinline__ float base80(const float* a)
{
    float r0=a[0],r1=a[1],r2=a[2],r3=a[3],r4=a[4],r5=a[5],r6=a[6],r7=a[7];
    #pragma unroll
    for (int i = 8; i < 80; i += 8) {
        r0=fa(r0,a[i+0]); r1=fa(r1,a[i+1]); r2=fa(r2,a[i+2]); r3=fa(r3,a[i+3]);
        r4=fa(r4,a[i+4]); r5=fa(r5,a[i+5]); r6=fa(r6,a[i+6]); r7=fa(r7,a[i+7]);
    }
    return fa(fa(fa(r0,r1),fa(r2,r3)), fa(fa(r4,r5),fa(r6,r7)));
}

// base80 over (a[i]-mu)^2, identical op order to the var phase
__device__ __forceinline__ float base80v(const float* a, float mu)
{
    float r[8];
    #pragma unroll
    for (int j = 0; j < 8; ++j) { const float d = fs(a[j], mu); r[j] = fm(d, d); }
    #pragma unroll
    for (int i = 8; i < 80; i += 8)
        #pragma unroll
        for (int j = 0; j < 8; ++j) {
            const float d = fs(a[i + j], mu);
            r[j] = fa(r[j], fm(d, d));
        }
    return fa(fa(fa(r[0],r[1]),fa(r[2],r[3])), fa(fa(r[4],r[5]),fa(r[6],r[7])));
}

// =========================================================================
// Kernel T: W[o][c] -> Wt[fc][o]  (exact copy; enables coalesced kA reads)
// =========================================================================
__global__ __launch_bounds__(256) void kT(const float* __restrict__ W,
                                          float* __restrict__ Wt)
{
    const int i = blockIdx.x * 256 + threadIdx.x;   // 0..32767 = fc*128+o
    const int fc = i >> 7, o = i & 127;
    Wt[i] = W[o * 256 + fc];
}

// =========================================================================
// Kernel A: np-mimic fp32 fusion matmul + GN1, two-phase K-staging.
// __launch_bounds__(128, 8): force <=64 VGPR -> 8 waves/SIMD cap; with
// 12.3 KB LDS the occupancy cap becomes 24 waves/CU (was 12-16).
// Math / chain order identical to the passing kernel (bit-exact).
// =========================================================================
__global__ __launch_bounds__(128, 8) void kA(const float* __restrict__ x,
                                             const float* __restrict__ Wt,
                                             const float* __restrict__ g1w,
                                             const float* __restrict__ g1b,
                                             float* __restrict__ y1)
{
    const int n0   = blockIdx.x * 4;
    const int tid  = threadIdx.x;
    const int lane = tid & 63;
    const int wv   = tid >> 6;             // wave id == sample-pair id

    __shared__ __align__(16) float xs[128 * 2 * 12];   // 12288 B
    __shared__ float statA[4][4];
    __shared__ float muS[4], rstdS[4];

    f32x2 accA[NV], accB[NV];
    #pragma unroll
    for (int v = 0; v < NV; ++v) { accA[v] = (f32x2){0.f,0.f}; accB[v] = (f32x2){0.f,0.f}; }

    const float* xrow = xs + wv * 12;

    #pragma unroll
    for (int ph = 0; ph < 2; ++ph) {
        // ---- stage this fc-half: wave-private region, predicated scatter
        {
            const float4* g0 = (const float4*)(x + (size_t)(n0 + 2 * wv) * 1280);
            const float4* g1 = g0 + 320;
            #pragma unroll
            for (int it = 0; it < 5; ++it) {
                const int k = it * 64 + lane;          // quad index 0..319
                const float4 a = g0[k];
                const float4 b = g1[k];
                const float av[4] = {a.x, a.y, a.z, a.w};
                const float bv[4] = {b.x, b.y, b.z, b.w};
                int f = k * 4;
                #pragma unroll
                for (int e = 0; e < 4; ++e, ++f) {
                    const int c  = f / 10;
                    const int j  = f - c * 10;
                    const int v  = (j < 5) ? j : j - 5;
                    const int fc = (j < 5) ? c : c + 128;
                    if ((fc >> 7) == ph) {
                        f32x2 pr; pr.x = av[e]; pr.y = bv[e];
                        *(f32x2*)&xs[((fc & 127) * 2 + wv) * 12 + v * 2] = pr;
                    }
                }
            }
        }

        // ---- matmul over this half: fc ascending (global order preserved)
        #pragma unroll 2
        for (int fc2 = 0; fc2 < 128; ++fc2) {
            const int fco = ph * 128 + fc2;
            const float wa = Wt[fco * 128 + lane];        // coalesced, L1/L2
            const float wb = Wt[fco * 128 + 64 + lane];
            const f32x4 Q0 = *(const f32x4*)&xrow[fc2 * 24];       // v0,v1
            const f32x4 Q1 = *(const f32x4*)&xrow[fc2 * 24 + 4];   // v2,v3
            const f32x2 P4 = *(const f32x2*)&xrow[fc2 * 24 + 8];   // v4
            f32x2 wpa; wpa.x = wa; wpa.y = wa;
            f32x2 wpb; wpb.x = wb; wpb.y = wb;
            const f32x2 p0 = __builtin_shufflevector(Q0, Q0, 0, 1);
            const f32x2 p1 = __builtin_shufflevector(Q0, Q0, 2, 3);
            const f32x2 p2 = __builtin_shufflevector(Q1, Q1, 0, 1);
            const f32x2 p3 = __builtin_shufflevector(Q1, Q1, 2, 3);
            accA[0] = pkadd(accA[0], pkmul(wpa, p0));
            accA[1] = pkadd(accA[1], pkmul(wpa, p1));
            accA[2] = pkadd(accA[2], pkmul(wpa, p2));
            accA[3] = pkadd(accA[3], pkmul(wpa, p3));
            accA[4] = pkadd(accA[4], pkmul(wpa, P4));
            accB[0] = pkadd(accB[0], pkmul(wpb, p0));
            accB[1] = pkadd(accB[1], pkmul(wpb, p1));
            accB[2] = pkadd(accB[2], pkmul(wpb, p2));
            accB[3] = pkadd(accB[3], pkmul(wpb, p3));
            accB[4] = pkadd(accB[4], pkmul(wpb, P4));
        }
    }
    __syncthreads();   // other wave may still read xs; wait before ys reuse

    float* ys = xs;    // [4][640] = 2560 floats <= 3072 available ✓

    #pragma unroll
    for (int sl = 0; sl < 2; ++sl) {
        const int g = wv * 2 + sl;
        #pragma unroll
        for (int v = 0; v < NV; ++v) {
            ys[g * 640 + lane * 5 + v]        = sl ? accA[v].y : accA[v].x;
            ys[g * 640 + (lane + 64) * 5 + v] = sl ? accB[v].y : accB[v].x;
        }
    }
    __syncthreads();

    // mean: numpy pairwise over 640 (o-major order)
    if (tid < 16) {
        const int g = tid >> 2, p = tid & 3;
        const float b0 = base80(&ys[g * 640 + (2 * p) * 80]);
        const float b1 = base80(&ys[g * 640 + (2 * p + 1) * 80]);
        statA[g][p] = fa(b0, b1);
    }
    __syncthreads();
    if (tid < 4) {
        const int g = tid;
        const float tot = fa(fa(statA[g][0], statA[g][1]), fa(statA[g][2], statA[g][3]));
        muS[g] = __fdiv_rn(tot, 640.f);
    }
    __syncthreads();

    // var: overwrite ys with (a - mu)^2, pairwise / 640
    #pragma unroll
    for (int sl = 0; sl < 2; ++sl) {
        const int g = wv * 2 + sl;
        const float mu = muS[g];
        #pragma unroll
        for (int v = 0; v < NV; ++v) {
            const float aA = sl ? accA[v].y : accA[v].x;
            const float aB = sl ? accB[v].y : accB[v].x;
            const float dA = fs(aA, mu);
            const float dB = fs(aB, mu);
            ys[g * 640 + lane * 5 + v]        = fm(dA, dA);
            ys[g * 640 + (lane + 64) * 5 + v] = fm(dB, dB);
        }
    }
    __syncthreads();
    if (tid < 16) {
        const int g = tid >> 2, p = tid & 3;
        const float b0 = base80(&ys[g * 640 + (2 * p) * 80]);
        const float b1 = base80(&ys[g * 640 + (2 * p + 1) * 80]);
        statA[g][p] = fa(b0, b1);
    }
    __syncthreads();
    if (tid < 4) {
        const int g = tid;
        const float tot = fa(fa(statA[g][0], statA[g][1]), fa(statA[g][2], statA[g][3]));
        const float var = __fdiv_rn(tot, 640.f);
        rstdS[g] = __fdiv_rn(1.f, __fsqrt_rn(fa(var, 1e-5f)));
    }
    __syncthreads();

    #pragma unroll
    for (int ch = 0; ch < 2; ++ch) {
        const int o = lane + ch * 64;
        const float wf = g1w[o], bf = g1b[o];
        #pragma unroll
        for (int sl = 0; sl < 2; ++sl) {
            const int g = wv * 2 + sl;
            const float mu = muS[g], rstd = rstdS[g];
            const int n = n0 + g;
            #pragma unroll
            for (int v = 0; v < NV; ++v) {
                const float av = ch ? (sl ? accB[v].y : accB[v].x)
                                    : (sl ? accA[v].y : accA[v].x);
                const float xn = fm(fs(av, mu), rstd);
                y1[(size_t)n * 640 + o * 5 + v] = fa(fm(xn, wf), bf);
            }
        }
    }
}

// =========================================================================
// Kernel B1: LIF1 (fp32, identical chain) -> ulonglong2 spike masks.
// =========================================================================
__global__ __launch_bounds__(320) void kB1(const float* __restrict__ y1,
                                           ulonglong2* __restrict__ masks)
{
    const int b   = blockIdx.x >> 1;
    const int c0  = (blockIdx.x & 1) * 64;
    const int tid = threadIdx.x;           // 0..319

    ull lo = 0ull, hi = 0ull;
    float vm = 0.f;
    const float* p = y1 + (size_t)b * 640 + (size_t)c0 * 5 + tid;
    for (int t0 = 0; t0 < NT; t0 += 16) {
        float xv[16];
        #pragma unroll
        for (int j = 0; j < 16; ++j)
            xv[j] = p[(size_t)(t0 + j) * (NB * 640)];
        #pragma unroll
        for (int j = 0; j < 16; ++j) {
            vm = fa(vm, fm(fs(xv[j], vm), 0.5f));
            if (vm >= 0.8f) {
                const int t = t0 + j;
                if (t < 64) lo |= 1ull << t; else hi |= 1ull << (t - 64);
                vm = 0.f;
            }
        }
    }
    masks[(size_t)b * 640 + (size_t)c0 * 5 + tid] = make_ulonglong2(lo, hi);
}

// =========================================================================
// Kernel B2: conv once (LDS) -> pairwise GN2 -> LIF2 -> coalesced stores.
// =========================================================================
__device__ __forceinline__ float bitf(ull lo, ull hi, int t)
{
    if (t < 0 || t > 127) return 0.f;
    return (float)(((t < 64) ? (lo >> t) : (hi >> (t - 64))) & 1ull);
}

__global__ __launch_bounds__(512) void kB2(const ulonglong2* __restrict__ masks,
                                           const float* __restrict__ Wm,
                                           const float* __restrict__ g2w,
                                           const float* __restrict__ g2b,
                                           const float* __restrict__ adj,
                                           float* __restrict__ out)
{
    const int blk = blockIdx.x;            // 0..4095
    const int b   = blk >> 5;              // 0..127
    const int c0  = (blk & 31) * 4;        // 0,4,..,124
    const int tid = threadIdx.x;           // 0..511
    const int p   = tid >> 7;              // pair 0..3
    const int lt  = tid & 127;             // t index / worker id

    __shared__ float mw_s[75];
    __shared__ ull   m_lo[4][5], m_hi[4][5];
    __shared__ float conv_s[4][5][128];
    __shared__ float spk_s[128][40];
    __shared__ float stat_s[4][8];
    __shared__ float mu_s[4], rstd_s[4];

    if (tid < 75) {
        const int oo = tid / 15, rem = tid % 15, ii = rem / 3;
        const float sym = fm(0.5f, fa(adj[oo * 5 + ii], adj[ii * 5 + oo]));
        const float e = (float)exp(-(double)sym);
        const float sig = __fdiv_rn(1.f, fa(1.f, e));
        mw_s[tid] = fm(Wm[tid], sig);
    }
    if (tid < 20) {
        const int pp = tid / 5, vv = tid % 5;
        const ulonglong2 m = masks[((size_t)b * 128 + c0 + pp) * 5 + vv];
        m_lo[pp][vv] = m.x; m_hi[pp][vv] = m.y;
    }
    __syncthreads();

    // ---- conv once: thread (p, t=lt); 15 shared bit extracts, 5 nodes
    {
        float bv[5][3];
        #pragma unroll
        for (int i = 0; i < 5; ++i) {
            const ull lo = m_lo[p][i], hi = m_hi[p][i];
            #pragma unroll
            for (int k = 0; k < 3; ++k)
                bv[i][k] = bitf(lo, hi, lt - 1 + k);
        }
        #pragma unroll
        for (int o = 0; o < 5; ++o) {
            float res = 0.f;
            #pragma unroll
            for (int i = 0; i < 5; ++i)
                #pragma unroll
                for (int k = 0; k < 3; ++k)
                    res = fa(res, fm(mw_s[(o * 5 + i) * 3 + k], bv[i][k]));
            conv_s[p][o][lt] = res;
        }
    }
    __syncthreads();

    // ---- GN2 mean
    if (lt < 8)
        stat_s[p][lt] = base80(&conv_s[p][0][0] + lt * 80);
    __syncthreads();
    if (lt == 0) {
        const float* s = stat_s[p];
        const float tot = fa(fa(fa(s[0],s[1]),fa(s[2],s[3])),
                             fa(fa(s[4],s[5]),fa(s[6],s[7])));
        mu_s[p] = __fdiv_rn(tot, 640.f);
    }
    __syncthreads();

    // ---- GN2 var
    if (lt < 8)
        stat_s[p][lt] = base80v(&conv_s[p][0][0] + lt * 80, mu_s[p]);
    __syncthreads();
    if (lt == 0) {
        const float* s = stat_s[p];
        const float tot = fa(fa(fa(s[0],s[1]),fa(s[2],s[3])),
                             fa(fa(s[4],s[5]),fa(s[6],s[7])));
        const float var = __fdiv_rn(tot, 640.f);
        rstd_s[p] = __fdiv_rn(1.f, __fsqrt_rn(fa(var, 1e-5f)));
    }
    __syncthreads();

    // ---- LIF2: 5 threads per pair (o = lt), spikes -> LDS
    if (lt < 5) {
        const int o = lt;
        const float mu = mu_s[p], rstd = rstd_s[p];
        const float gw = g2w[o], gb = g2b[o];
        float vm = 0.f;
        for (int t = 0; t < NT; ++t) {
            const float z  = conv_s[p][o][t];
            const float xn = fm(fs(z, mu), rstd);
            const float yn = fa(fm(xn, gw), gb);
            vm = fa(vm, fm(fs(yn, vm), 0.5f));
            const bool sp = (vm >= 0.8f);
            if (sp) vm = 0.f;
            const float so = sp ? 1.f : 0.f;
            spk_s[t][p * 10 + o]     = so;
            spk_s[t][p * 10 + 5 + o] = so;
        }
    }
    __syncthreads();

    // ---- coalesced store
    for (int q = tid; q < 1280; q += 512) {
        const int t = q / 10, s = q - t * 10;
        float4* dst = (float4*)(out + ((size_t)(t * NB + b) * 1280 + c0 * 10));
        dst[s] = reinterpret_cast<const float4*>(&spk_s[t][0])[s];
    }
}

// =========================================================================
extern "C" void kernel_launch(void* const* d_in, const int* in_sizes, int n_in,
                              void* d_out, int out_size, void* d_ws, size_t ws_size,
                              hipStream_t stream)
{
    const float* x   = (const float*)d_in[0];
    const float* W   = (const float*)d_in[1];
    const float* g1w = (const float*)d_in[2];
    const float* g1b = (const float*)d_in[3];
    const float* Wm  = (const float*)d_in[4];
    const float* g2w = (const float*)d_in[5];
    const float* g2b = (const float*)d_in[6];
    const float* adj = (const float*)d_in[7];
    float* out = (float*)d_out;

    float* y1 = (float*)d_ws;                                     // 41.9 MB
    ulonglong2* masks = (ulonglong2*)((char*)d_ws + (64u << 20)); // 1.3 MB
    float* Wt = (float*)((char*)d_ws + (80u << 20));              // 128 KB

    hipLaunchKernelGGL(kT, dim3(128), dim3(256), 0, stream, W, Wt);
    hipLaunchKernelGGL(kA, dim3(NT * NB / 4), dim3(128), 0, stream,
                       x, Wt, g1w, g1b, y1);
    hipLaunchKernelGGL(kB1, dim3(NB * 2), dim3(320), 0, stream,
                       y1, masks);
    hipLaunchKernelGGL(kB2, dim3(4096), dim3(512), 0, stream,
                       masks, Wm, g2w, g2b, adj, out);
}

// Round 19
// 199.697 us; speedup vs baseline: 1.1914x; 1.1910x over previous
//
#include <hip/hip_runtime.h>
#include <cstdint>
#include <cstddef>

#define NV 5
#define NC 128
#define NT 128
#define NB 128
typedef unsigned long long ull;
typedef float f32x2 __attribute__((ext_vector_type(2)));
typedef float f32x4 __attribute__((ext_vector_type(4)));

__device__ __forceinline__ float fa(float a, float b){ return __fadd_rn(a,b); }
__device__ __forceinline__ float fm(float a, float b){ return __fmul_rn(a,b); }
__device__ __forceinline__ float fs(float a, float b){ return __fsub_rn(a,b); }

// packed fp32: two independent IEEE-RNE ops per instruction (bit-identical
// to v_mul_f32/v_add_f32 per half)
__device__ __forceinline__ f32x2 pkmul(f32x2 a, f32x2 b){
    f32x2 d; asm("v_pk_mul_f32 %0, %1, %2" : "=v"(d) : "v"(a), "v"(b)); return d;
}
__device__ __forceinline__ f32x2 pkadd(f32x2 a, f32x2 b){
    f32x2 d; asm("v_pk_add_f32 %0, %1, %2" : "=v"(d) : "v"(a), "v"(b)); return d;
}

// numpy pairwise_sum base case, n=80, contiguous fp32
__device__ __forceinline__ float base80(const float* a)
{
    float r0=a[0],r1=a[1],r2=a[2],r3=a[3],r4=a[4],r5=a[5],r6=a[6],r7=a[7];
    #pragma unroll
    for (int i = 8; i < 80; i += 8) {
        r0=fa(r0,a[i+0]); r1=fa(r1,a[i+1]); r2=fa(r2,a[i+2]); r3=fa(r3,a[i+3]);
        r4=fa(r4,a[i+4]); r5=fa(r5,a[i+5]); r6=fa(r6,a[i+6]); r7=fa(r7,a[i+7]);
    }
    return fa(fa(fa(r0,r1),fa(r2,r3)), fa(fa(r4,r5),fa(r6,r7)));
}

// base80 over (a[i]-mu)^2, identical op order to the var phase
__device__ __forceinline__ float base80v(const float* a, float mu)
{
    float r[8];
    #pragma unroll
    for (int j = 0; j < 8; ++j) { const float d = fs(a[j], mu); r[j] = fm(d, d); }
    #pragma unroll
    for (int i = 8; i < 80; i += 8)
        #pragma unroll
        for (int j = 0; j < 8; ++j) {
            const float d = fs(a[i + j], mu);
            r[j] = fa(r[j], fm(d, d));
        }
    return fa(fa(fa(r[0],r[1]),fa(r[2],r[3])), fa(fa(r[4],r[5]),fa(r[6],r[7])));
}

// =========================================================================
// Kernel T: W[o][c] -> Wt[fc][o]  (exact copy; enables coalesced kA reads)
// =========================================================================
__global__ __launch_bounds__(256) void kT(const float* __restrict__ W,
                                          float* __restrict__ Wt)
{
    const int i = blockIdx.x * 256 + threadIdx.x;   // 0..32767 = fc*128+o
    const int fc = i >> 7, o = i & 127;
    Wt[i] = W[o * 256 + fc];
}

// =========================================================================
// Kernel A: np-mimic fp32 fusion matmul + GN1 (R14 structure, best known;
// only change: fc-loop unroll 4). 128 threads = 2 waves; wave wv owns
// samples {2wv,2wv+1}; thread owns channels {lane, lane+64}. LDS
// xs[fc][wv][v] = f32x2 (s0,s1) pairs -> b128/b64 broadcast reads feed
// v_pk math (halves = independent chains -> bit-exact).
// =========================================================================
__global__ __launch_bounds__(128) void kA(const float* __restrict__ x,
                                          const float* __restrict__ Wt,
                                          const float* __restrict__ g1w,
                                          const float* __restrict__ g1b,
                                          float* __restrict__ y1)
{
    const int n0   = blockIdx.x * 4;
    const int tid  = threadIdx.x;
    const int lane = tid & 63;
    const int wv   = tid >> 6;             // wave id == sample-pair id

    __shared__ __align__(16) float xs[256 * 2 * 12];   // 24576 B
    __shared__ float statA[4][4];
    __shared__ float muS[4], rstdS[4];

    // ---- stage: wave wv stages its samples {2wv, 2wv+1} as (s0,s1) pairs.
    // Wave-private region; same-wave DS ordering -> no barrier before matmul.
    {
        const float4* g0 = (const float4*)(x + (size_t)(n0 + 2 * wv) * 1280);
        const float4* g1 = g0 + 320;
        #pragma unroll
        for (int it = 0; it < 5; ++it) {
            const int k = it * 64 + lane;          // quad index 0..319
            const float4 a = g0[k];
            const float4 b = g1[k];
            const float av[4] = {a.x, a.y, a.z, a.w};
            const float bv[4] = {b.x, b.y, b.z, b.w};
            int f = k * 4;                          // flat idx in sample row
            #pragma unroll
            for (int e = 0; e < 4; ++e, ++f) {
                const int c  = f / 10;
                const int j  = f - c * 10;
                const int v  = (j < 5) ? j : j - 5;
                const int fc = (j < 5) ? c : c + 128;
                f32x2 pr; pr.x = av[e]; pr.y = bv[e];
                *(f32x2*)&xs[(fc * 2 + wv) * 12 + v * 2] = pr;  // b64
            }
        }
    }

    // ---- matmul: fc sequential 0..255 (acc half then gyr half); packed.
    // Each f32x2 half is an independent per-output chain -> bit-exact.
    f32x2 accA[NV], accB[NV];
    #pragma unroll
    for (int v = 0; v < NV; ++v) { accA[v] = (f32x2){0.f,0.f}; accB[v] = (f32x2){0.f,0.f}; }

    const float* xrow = xs + wv * 12;
    #pragma unroll 4
    for (int fc = 0; fc < 256; ++fc) {
        const float wa = Wt[fc * 128 + lane];        // coalesced, L1/L2
        const float wb = Wt[fc * 128 + 64 + lane];
        const f32x4 Q0 = *(const f32x4*)&xrow[fc * 24];       // v0,v1 pairs
        const f32x4 Q1 = *(const f32x4*)&xrow[fc * 24 + 4];   // v2,v3 pairs
        const f32x2 P4 = *(const f32x2*)&xrow[fc * 24 + 8];   // v4 pair
        f32x2 wpa; wpa.x = wa; wpa.y = wa;
        f32x2 wpb; wpb.x = wb; wpb.y = wb;
        const f32x2 p0 = __builtin_shufflevector(Q0, Q0, 0, 1);
        const f32x2 p1 = __builtin_shufflevector(Q0, Q0, 2, 3);
        const f32x2 p2 = __builtin_shufflevector(Q1, Q1, 0, 1);
        const f32x2 p3 = __builtin_shufflevector(Q1, Q1, 2, 3);
        accA[0] = pkadd(accA[0], pkmul(wpa, p0));
        accA[1] = pkadd(accA[1], pkmul(wpa, p1));
        accA[2] = pkadd(accA[2], pkmul(wpa, p2));
        accA[3] = pkadd(accA[3], pkmul(wpa, p3));
        accA[4] = pkadd(accA[4], pkmul(wpa, P4));
        accB[0] = pkadd(accB[0], pkmul(wpb, p0));
        accB[1] = pkadd(accB[1], pkmul(wpb, p1));
        accB[2] = pkadd(accB[2], pkmul(wpb, p2));
        accB[3] = pkadd(accB[3], pkmul(wpb, p3));
        accB[4] = pkadd(accB[4], pkmul(wpb, P4));
    }
    __syncthreads();   // other wave may still read xs; wait before ys reuse

    float* ys = xs;    // [4][640] stats buffer (reused region)

    #pragma unroll
    for (int sl = 0; sl < 2; ++sl) {
        const int g = wv * 2 + sl;
        #pragma unroll
        for (int v = 0; v < NV; ++v) {
            ys[g * 640 + lane * 5 + v]        = sl ? accA[v].y : accA[v].x;
            ys[g * 640 + (lane + 64) * 5 + v] = sl ? accB[v].y : accB[v].x;
        }
    }
    __syncthreads();

    // mean: numpy pairwise over 640 (o-major order)
    if (tid < 16) {
        const int g = tid >> 2, p = tid & 3;
        const float b0 = base80(&ys[g * 640 + (2 * p) * 80]);
        const float b1 = base80(&ys[g * 640 + (2 * p + 1) * 80]);
        statA[g][p] = fa(b0, b1);
    }
    __syncthreads();
    if (tid < 4) {
        const int g = tid;
        const float tot = fa(fa(statA[g][0], statA[g][1]), fa(statA[g][2], statA[g][3]));
        muS[g] = __fdiv_rn(tot, 640.f);
    }
    __syncthreads();

    // var: overwrite ys with (a - mu)^2, pairwise / 640
    #pragma unroll
    for (int sl = 0; sl < 2; ++sl) {
        const int g = wv * 2 + sl;
        const float mu = muS[g];
        #pragma unroll
        for (int v = 0; v < NV; ++v) {
            const float aA = sl ? accA[v].y : accA[v].x;
            const float aB = sl ? accB[v].y : accB[v].x;
            const float dA = fs(aA, mu);
            const float dB = fs(aB, mu);
            ys[g * 640 + lane * 5 + v]        = fm(dA, dA);
            ys[g * 640 + (lane + 64) * 5 + v] = fm(dB, dB);
        }
    }
    __syncthreads();
    if (tid < 16) {
        const int g = tid >> 2, p = tid & 3;
        const float b0 = base80(&ys[g * 640 + (2 * p) * 80]);
        const float b1 = base80(&ys[g * 640 + (2 * p + 1) * 80]);
        statA[g][p] = fa(b0, b1);
    }
    __syncthreads();
    if (tid < 4) {
        const int g = tid;
        const float tot = fa(fa(statA[g][0], statA[g][1]), fa(statA[g][2], statA[g][3]));
        const float var = __fdiv_rn(tot, 640.f);
        rstdS[g] = __fdiv_rn(1.f, __fsqrt_rn(fa(var, 1e-5f)));
    }
    __syncthreads();

    #pragma unroll
    for (int ch = 0; ch < 2; ++ch) {
        const int o = lane + ch * 64;
        const float wf = g1w[o], bf = g1b[o];
        #pragma unroll
        for (int sl = 0; sl < 2; ++sl) {
            const int g = wv * 2 + sl;
            const float mu = muS[g], rstd = rstdS[g];
            const int n = n0 + g;
            #pragma unroll
            for (int v = 0; v < NV; ++v) {
                const float av = ch ? (sl ? accB[v].y : accB[v].x)
                                    : (sl ? accA[v].y : accA[v].x);
                const float xn = fm(fs(av, mu), rstd);
                y1[(size_t)n * 640 + o * 5 + v] = fa(fm(xn, wf), bf);
            }
        }
    }
}

// =========================================================================
// Kernel B1: LIF1 (fp32, identical chain) -> ulonglong2 spike masks.
// =========================================================================
__global__ __launch_bounds__(320) void kB1(const float* __restrict__ y1,
                                           ulonglong2* __restrict__ masks)
{
    const int b   = blockIdx.x >> 1;
    const int c0  = (blockIdx.x & 1) * 64;
    const int tid = threadIdx.x;           // 0..319

    ull lo = 0ull, hi = 0ull;
    float vm = 0.f;
    const float* p = y1 + (size_t)b * 640 + (size_t)c0 * 5 + tid;
    for (int t0 = 0; t0 < NT; t0 += 16) {
        float xv[16];
        #pragma unroll
        for (int j = 0; j < 16; ++j)
            xv[j] = p[(size_t)(t0 + j) * (NB * 640)];
        #pragma unroll
        for (int j = 0; j < 16; ++j) {
            vm = fa(vm, fm(fs(xv[j], vm), 0.5f));
            if (vm >= 0.8f) {
                const int t = t0 + j;
                if (t < 64) lo |= 1ull << t; else hi |= 1ull << (t - 64);
                vm = 0.f;
            }
        }
    }
    masks[(size_t)b * 640 + (size_t)c0 * 5 + tid] = make_ulonglong2(lo, hi);
}

// =========================================================================
// Kernel B2: conv once (LDS) -> pairwise GN2 -> LIF2 -> coalesced stores.
// =========================================================================
__device__ __forceinline__ float bitf(ull lo, ull hi, int t)
{
    if (t < 0 || t > 127) return 0.f;
    return (float)(((t < 64) ? (lo >> t) : (hi >> (t - 64))) & 1ull);
}

__global__ __launch_bounds__(512) void kB2(const ulonglong2* __restrict__ masks,
                                           const float* __restrict__ Wm,
                                           const float* __restrict__ g2w,
                                           const float* __restrict__ g2b,
                                           const float* __restrict__ adj,
                                           float* __restrict__ out)
{
    const int blk = blockIdx.x;            // 0..4095
    const int b   = blk >> 5;              // 0..127
    const int c0  = (blk & 31) * 4;        // 0,4,..,124
    const int tid = threadIdx.x;           // 0..511
    const int p   = tid >> 7;              // pair 0..3
    const int lt  = tid & 127;             // t index / worker id

    __shared__ float mw_s[75];
    __shared__ ull   m_lo[4][5], m_hi[4][5];
    __shared__ float conv_s[4][5][128];
    __shared__ float spk_s[128][40];
    __shared__ float stat_s[4][8];
    __shared__ float mu_s[4], rstd_s[4];

    if (tid < 75) {
        const int oo = tid / 15, rem = tid % 15, ii = rem / 3;
        const float sym = fm(0.5f, fa(adj[oo * 5 + ii], adj[ii * 5 + oo]));
        const float e = (float)exp(-(double)sym);
        const float sig = __fdiv_rn(1.f, fa(1.f, e));
        mw_s[tid] = fm(Wm[tid], sig);
    }
    if (tid < 20) {
        const int pp = tid / 5, vv = tid % 5;
        const ulonglong2 m = masks[((size_t)b * 128 + c0 + pp) * 5 + vv];
        m_lo[pp][vv] = m.x; m_hi[pp][vv] = m.y;
    }
    __syncthreads();

    // ---- conv once: thread (p, t=lt); 15 shared bit extracts, 5 nodes
    {
        float bv[5][3];
        #pragma unroll
        for (int i = 0; i < 5; ++i) {
            const ull lo = m_lo[p][i], hi = m_hi[p][i];
            #pragma unroll
            for (int k = 0; k < 3; ++k)
                bv[i][k] = bitf(lo, hi, lt - 1 + k);
        }
        #pragma unroll
        for (int o = 0; o < 5; ++o) {
            float res = 0.f;
            #pragma unroll
            for (int i = 0; i < 5; ++i)
                #pragma unroll
                for (int k = 0; k < 3; ++k)
                    res = fa(res, fm(mw_s[(o * 5 + i) * 3 + k], bv[i][k]));
            conv_s[p][o][lt] = res;
        }
    }
    __syncthreads();

    // ---- GN2 mean
    if (lt < 8)
        stat_s[p][lt] = base80(&conv_s[p][0][0] + lt * 80);
    __syncthreads();
    if (lt == 0) {
        const float* s = stat_s[p];
        const float tot = fa(fa(fa(s[0],s[1]),fa(s[2],s[3])),
                             fa(fa(s[4],s[5]),fa(s[6],s[7])));
        mu_s[p] = __fdiv_rn(tot, 640.f);
    }
    __syncthreads();

    // ---- GN2 var
    if (lt < 8)
        stat_s[p][lt] = base80v(&conv_s[p][0][0] + lt * 80, mu_s[p]);
    __syncthreads();
    if (lt == 0) {
        const float* s = stat_s[p];
        const float tot = fa(fa(fa(s[0],s[1]),fa(s[2],s[3])),
                             fa(fa(s[4],s[5]),fa(s[6],s[7])));
        const float var = __fdiv_rn(tot, 640.f);
        rstd_s[p] = __fdiv_rn(1.f, __fsqrt_rn(fa(var, 1e-5f)));
    }
    __syncthreads();

    // ---- LIF2: 5 threads per pair (o = lt), spikes -> LDS
    if (lt < 5) {
        const int o = lt;
        const float mu = mu_s[p], rstd = rstd_s[p];
        const float gw = g2w[o], gb = g2b[o];
        float vm = 0.f;
        for (int t = 0; t < NT; ++t) {
            const float z  = conv_s[p][o][t];
            const float xn = fm(fs(z, mu), rstd);
            const float yn = fa(fm(xn, gw), gb);
            vm = fa(vm, fm(fs(yn, vm), 0.5f));
            const bool sp = (vm >= 0.8f);
            if (sp) vm = 0.f;
            const float so = sp ? 1.f : 0.f;
            spk_s[t][p * 10 + o]     = so;
            spk_s[t][p * 10 + 5 + o] = so;
        }
    }
    __syncthreads();

    // ---- coalesced store
    for (int q = tid; q < 1280; q += 512) {
        const int t = q / 10, s = q - t * 10;
        float4* dst = (float4*)(out + ((size_t)(t * NB + b) * 1280 + c0 * 10));
        dst[s] = reinterpret_cast<const float4*>(&spk_s[t][0])[s];
    }
}

// =========================================================================
extern "C" void kernel_launch(void* const* d_in, const int* in_sizes, int n_in,
                              void* d_out, int out_size, void* d_ws, size_t ws_size,
                              hipStream_t stream)
{
    const float* x   = (const float*)d_in[0];
    const float* W   = (const float*)d_in[1];
    const float* g1w = (const float*)d_in[2];
    const float* g1b = (const float*)d_in[3];
    const float* Wm  = (const float*)d_in[4];
    const float* g2w = (const float*)d_in[5];
    const float* g2b = (const float*)d_in[6];
    const float* adj = (const float*)d_in[7];
    float* out = (float*)d_out;

    float* y1 = (float*)d_ws;                                     // 41.9 MB
    ulonglong2* masks = (ulonglong2*)((char*)d_ws + (64u << 20)); // 1.3 MB
    float* Wt = (float*)((char*)d_ws + (80u << 20));              // 128 KB

    hipLaunchKernelGGL(kT, dim3(128), dim3(256), 0, stream, W, Wt);
    hipLaunchKernelGGL(kA, dim3(NT * NB / 4), dim3(128), 0, stream,
                       x, Wt, g1w, g1b, y1);
    hipLaunchKernelGGL(kB1, dim3(NB * 2), dim3(320), 0, stream,
                       y1, masks);
    hipLaunchKernelGGL(kB2, dim3(4096), dim3(512), 0, stream,
                       masks, Wm, g2w, g2b, adj, out);
}

// Round 20
// 188.037 us; speedup vs baseline: 1.2653x; 1.0620x over previous
//
#include <hip/hip_runtime.h>
#include <cstdint>
#include <cstddef>

#define NV 5
#define NC 128
#define NT 128
#define NB 128
typedef unsigned long long ull;
typedef float f32x2 __attribute__((ext_vector_type(2)));
typedef float f32x4 __attribute__((ext_vector_type(4)));

__device__ __forceinline__ float fa(float a, float b){ return __fadd_rn(a,b); }
__device__ __forceinline__ float fm(float a, float b){ return __fmul_rn(a,b); }
__device__ __forceinline__ float fs(float a, float b){ return __fsub_rn(a,b); }

// packed fp32: two independent IEEE-RNE ops per instruction (bit-identical
// to v_mul_f32/v_add_f32 per half)
__device__ __forceinline__ f32x2 pkmul(f32x2 a, f32x2 b){
    f32x2 d; asm("v_pk_mul_f32 %0, %1, %2" : "=v"(d) : "v"(a), "v"(b)); return d;
}
__device__ __forceinline__ f32x2 pkadd(f32x2 a, f32x2 b){
    f32x2 d; asm("v_pk_add_f32 %0, %1, %2" : "=v"(d) : "v"(a), "v"(b)); return d;
}

// numpy pairwise_sum base case, n=80, contiguous fp32
__device__ __forceinline__ float base80(const float* a)
{
    float r0=a[0],r1=a[1],r2=a[2],r3=a[3],r4=a[4],r5=a[5],r6=a[6],r7=a[7];
    #pragma unroll
    for (int i = 8; i < 80; i += 8) {
        r0=fa(r0,a[i+0]); r1=fa(r1,a[i+1]); r2=fa(r2,a[i+2]); r3=fa(r3,a[i+3]);
        r4=fa(r4,a[i+4]); r5=fa(r5,a[i+5]); r6=fa(r6,a[i+6]); r7=fa(r7,a[i+7]);
    }
    return fa(fa(fa(r0,r1),fa(r2,r3)), fa(fa(r4,r5),fa(r6,r7)));
}

// base80 over (a[i]-mu)^2, identical op order to the var phase
__device__ __forceinline__ float base80v(const float* a, float mu)
{
    float r[8];
    #pragma unroll
    for (int j = 0; j < 8; ++j) { const float d = fs(a[j], mu); r[j] = fm(d, d); }
    #pragma unroll
    for (int i = 8; i < 80; i += 8)
        #pragma unroll
        for (int j = 0; j < 8; ++j) {
            const float d = fs(a[i + j], mu);
            r[j] = fa(r[j], fm(d, d));
        }
    return fa(fa(fa(r[0],r[1]),fa(r[2],r[3])), fa(fa(r[4],r[5]),fa(r[6],r[7])));
}

// =========================================================================
// Kernel T: W[o][c] -> Wt[fc][o]  (exact copy; enables coalesced kA reads)
// =========================================================================
__global__ __launch_bounds__(256) void kT(const float* __restrict__ W,
                                          float* __restrict__ Wt)
{
    const int i = blockIdx.x * 256 + threadIdx.x;   // 0..32767 = fc*128+o
    const int fc = i >> 7, o = i & 127;
    Wt[i] = W[o * 256 + fc];
}

// =========================================================================
// Kernel A: np-mimic fp32 fusion matmul + GN1 (R14 per-wave structure,
// 8 samples/block). 256 threads = 4 waves; wave wv owns samples
// {2wv,2wv+1}; thread owns channels {lane, lane+64}. LDS xs[fc][wv][v] =
// f32x2 (s0,s1) pairs. 4 waves walk the same Wt stream -> L1 temporal
// locality; total W traffic halves. Per-output fp32 op sequence identical
// to the passing kernel -> bit-exact.
// =========================================================================
__global__ __launch_bounds__(256) void kA(const float* __restrict__ x,
                                          const float* __restrict__ Wt,
                                          const float* __restrict__ g1w,
                                          const float* __restrict__ g1b,
                                          float* __restrict__ y1)
{
    const int n0   = blockIdx.x * 8;
    const int tid  = threadIdx.x;
    const int lane = tid & 63;
    const int wv   = tid >> 6;             // wave id == sample-pair id 0..3

    __shared__ __align__(16) float xs[256 * 4 * 12];   // 49152 B
    __shared__ float statA[8][4];
    __shared__ float muS[8], rstdS[8];

    // ---- stage: wave wv stages its samples {2wv, 2wv+1} as (s0,s1) pairs.
    // Wave-private region; same-wave DS ordering -> no barrier before matmul.
    {
        const float4* g0 = (const float4*)(x + (size_t)(n0 + 2 * wv) * 1280);
        const float4* g1 = g0 + 320;
        #pragma unroll
        for (int it = 0; it < 5; ++it) {
            const int k = it * 64 + lane;          // quad index 0..319
            const float4 a = g0[k];
            const float4 b = g1[k];
            const float av[4] = {a.x, a.y, a.z, a.w};
            const float bv[4] = {b.x, b.y, b.z, b.w};
            int f = k * 4;                          // flat idx in sample row
            #pragma unroll
            for (int e = 0; e < 4; ++e, ++f) {
                const int c  = f / 10;
                const int j  = f - c * 10;
                const int v  = (j < 5) ? j : j - 5;
                const int fc = (j < 5) ? c : c + 128;
                f32x2 pr; pr.x = av[e]; pr.y = bv[e];
                *(f32x2*)&xs[(fc * 4 + wv) * 12 + v * 2] = pr;  // b64
            }
        }
    }

    // ---- matmul: fc sequential 0..255 (acc half then gyr half); packed.
    // Each f32x2 half is an independent per-output chain -> bit-exact.
    f32x2 accA[NV], accB[NV];
    #pragma unroll
    for (int v = 0; v < NV; ++v) { accA[v] = (f32x2){0.f,0.f}; accB[v] = (f32x2){0.f,0.f}; }

    const float* xrow = xs + wv * 12;
    #pragma unroll 4
    for (int fc = 0; fc < 256; ++fc) {
        const float wa = Wt[fc * 128 + lane];        // coalesced, L1/L2
        const float wb = Wt[fc * 128 + 64 + lane];
        const f32x4 Q0 = *(const f32x4*)&xrow[fc * 48];       // v0,v1 pairs
        const f32x4 Q1 = *(const f32x4*)&xrow[fc * 48 + 4];   // v2,v3 pairs
        const f32x2 P4 = *(const f32x2*)&xrow[fc * 48 + 8];   // v4 pair
        f32x2 wpa; wpa.x = wa; wpa.y = wa;
        f32x2 wpb; wpb.x = wb; wpb.y = wb;
        const f32x2 p0 = __builtin_shufflevector(Q0, Q0, 0, 1);
        const f32x2 p1 = __builtin_shufflevector(Q0, Q0, 2, 3);
        const f32x2 p2 = __builtin_shufflevector(Q1, Q1, 0, 1);
        const f32x2 p3 = __builtin_shufflevector(Q1, Q1, 2, 3);
        accA[0] = pkadd(accA[0], pkmul(wpa, p0));
        accA[1] = pkadd(accA[1], pkmul(wpa, p1));
        accA[2] = pkadd(accA[2], pkmul(wpa, p2));
        accA[3] = pkadd(accA[3], pkmul(wpa, p3));
        accA[4] = pkadd(accA[4], pkmul(wpa, P4));
        accB[0] = pkadd(accB[0], pkmul(wpb, p0));
        accB[1] = pkadd(accB[1], pkmul(wpb, p1));
        accB[2] = pkadd(accB[2], pkmul(wpb, p2));
        accB[3] = pkadd(accB[3], pkmul(wpb, p3));
        accB[4] = pkadd(accB[4], pkmul(wpb, P4));
    }
    __syncthreads();   // other waves may still read xs; wait before ys reuse

    float* ys = xs;    // [8][640] = 5120 floats <= 12288 available ✓

    #pragma unroll
    for (int sl = 0; sl < 2; ++sl) {
        const int g = wv * 2 + sl;
        #pragma unroll
        for (int v = 0; v < NV; ++v) {
            ys[g * 640 + lane * 5 + v]        = sl ? accA[v].y : accA[v].x;
            ys[g * 640 + (lane + 64) * 5 + v] = sl ? accB[v].y : accB[v].x;
        }
    }
    __syncthreads();

    // mean: numpy pairwise over 640 (o-major order), 8 samples
    if (tid < 32) {
        const int g = tid >> 2, p = tid & 3;
        const float b0 = base80(&ys[g * 640 + (2 * p) * 80]);
        const float b1 = base80(&ys[g * 640 + (2 * p + 1) * 80]);
        statA[g][p] = fa(b0, b1);
    }
    __syncthreads();
    if (tid < 8) {
        const int g = tid;
        const float tot = fa(fa(statA[g][0], statA[g][1]), fa(statA[g][2], statA[g][3]));
        muS[g] = __fdiv_rn(tot, 640.f);
    }
    __syncthreads();

    // var: overwrite ys with (a - mu)^2, pairwise / 640
    #pragma unroll
    for (int sl = 0; sl < 2; ++sl) {
        const int g = wv * 2 + sl;
        const float mu = muS[g];
        #pragma unroll
        for (int v = 0; v < NV; ++v) {
            const float aA = sl ? accA[v].y : accA[v].x;
            const float aB = sl ? accB[v].y : accB[v].x;
            const float dA = fs(aA, mu);
            const float dB = fs(aB, mu);
            ys[g * 640 + lane * 5 + v]        = fm(dA, dA);
            ys[g * 640 + (lane + 64) * 5 + v] = fm(dB, dB);
        }
    }
    __syncthreads();
    if (tid < 32) {
        const int g = tid >> 2, p = tid & 3;
        const float b0 = base80(&ys[g * 640 + (2 * p) * 80]);
        const float b1 = base80(&ys[g * 640 + (2 * p + 1) * 80]);
        statA[g][p] = fa(b0, b1);
    }
    __syncthreads();
    if (tid < 8) {
        const int g = tid;
        const float tot = fa(fa(statA[g][0], statA[g][1]), fa(statA[g][2], statA[g][3]));
        const float var = __fdiv_rn(tot, 640.f);
        rstdS[g] = __fdiv_rn(1.f, __fsqrt_rn(fa(var, 1e-5f)));
    }
    __syncthreads();

    #pragma unroll
    for (int ch = 0; ch < 2; ++ch) {
        const int o = lane + ch * 64;
        const float wf = g1w[o], bf = g1b[o];
        #pragma unroll
        for (int sl = 0; sl < 2; ++sl) {
            const int g = wv * 2 + sl;
            const float mu = muS[g], rstd = rstdS[g];
            const int n = n0 + g;
            #pragma unroll
            for (int v = 0; v < NV; ++v) {
                const float av = ch ? (sl ? accB[v].y : accB[v].x)
                                    : (sl ? accA[v].y : accA[v].x);
                const float xn = fm(fs(av, mu), rstd);
                y1[(size_t)n * 640 + o * 5 + v] = fa(fm(xn, wf), bf);
            }
        }
    }
}

// =========================================================================
// Kernel B1: LIF1 (fp32, identical chain) -> ulonglong2 spike masks.
// =========================================================================
__global__ __launch_bounds__(320) void kB1(const float* __restrict__ y1,
                                           ulonglong2* __restrict__ masks)
{
    const int b   = blockIdx.x >> 1;
    const int c0  = (blockIdx.x & 1) * 64;
    const int tid = threadIdx.x;           // 0..319

    ull lo = 0ull, hi = 0ull;
    float vm = 0.f;
    const float* p = y1 + (size_t)b * 640 + (size_t)c0 * 5 + tid;
    for (int t0 = 0; t0 < NT; t0 += 16) {
        float xv[16];
        #pragma unroll
        for (int j = 0; j < 16; ++j)
            xv[j] = p[(size_t)(t0 + j) * (NB * 640)];
        #pragma unroll
        for (int j = 0; j < 16; ++j) {
            vm = fa(vm, fm(fs(xv[j], vm), 0.5f));
            if (vm >= 0.8f) {
                const int t = t0 + j;
                if (t < 64) lo |= 1ull << t; else hi |= 1ull << (t - 64);
                vm = 0.f;
            }
        }
    }
    masks[(size_t)b * 640 + (size_t)c0 * 5 + tid] = make_ulonglong2(lo, hi);
}

// =========================================================================
// Kernel B2: conv once (LDS) -> pairwise GN2 -> LIF2 -> coalesced stores.
// =========================================================================
__device__ __forceinline__ float bitf(ull lo, ull hi, int t)
{
    if (t < 0 || t > 127) return 0.f;
    return (float)(((t < 64) ? (lo >> t) : (hi >> (t - 64))) & 1ull);
}

__global__ __launch_bounds__(512) void kB2(const ulonglong2* __restrict__ masks,
                                           const float* __restrict__ Wm,
                                           const float* __restrict__ g2w,
                                           const float* __restrict__ g2b,
                                           const float* __restrict__ adj,
                                           float* __restrict__ out)
{
    const int blk = blockIdx.x;            // 0..4095
    const int b   = blk >> 5;              // 0..127
    const int c0  = (blk & 31) * 4;        // 0,4,..,124
    const int tid = threadIdx.x;           // 0..511
    const int p   = tid >> 7;              // pair 0..3
    const int lt  = tid & 127;             // t index / worker id

    __shared__ float mw_s[75];
    __shared__ ull   m_lo[4][5], m_hi[4][5];
    __shared__ float conv_s[4][5][128];
    __shared__ float spk_s[128][40];
    __shared__ float stat_s[4][8];
    __shared__ float mu_s[4], rstd_s[4];

    if (tid < 75) {
        const int oo = tid / 15, rem = tid % 15, ii = rem / 3;
        const float sym = fm(0.5f, fa(adj[oo * 5 + ii], adj[ii * 5 + oo]));
        const float e = (float)exp(-(double)sym);
        const float sig = __fdiv_rn(1.f, fa(1.f, e));
        mw_s[tid] = fm(Wm[tid], sig);
    }
    if (tid < 20) {
        const int pp = tid / 5, vv = tid % 5;
        const ulonglong2 m = masks[((size_t)b * 128 + c0 + pp) * 5 + vv];
        m_lo[pp][vv] = m.x; m_hi[pp][vv] = m.y;
    }
    __syncthreads();

    // ---- conv once: thread (p, t=lt); 15 shared bit extracts, 5 nodes
    {
        float bv[5][3];
        #pragma unroll
        for (int i = 0; i < 5; ++i) {
            const ull lo = m_lo[p][i], hi = m_hi[p][i];
            #pragma unroll
            for (int k = 0; k < 3; ++k)
                bv[i][k] = bitf(lo, hi, lt - 1 + k);
        }
        #pragma unroll
        for (int o = 0; o < 5; ++o) {
            float res = 0.f;
            #pragma unroll
            for (int i = 0; i < 5; ++i)
                #pragma unroll
                for (int k = 0; k < 3; ++k)
                    res = fa(res, fm(mw_s[(o * 5 + i) * 3 + k], bv[i][k]));
            conv_s[p][o][lt] = res;
        }
    }
    __syncthreads();

    // ---- GN2 mean
    if (lt < 8)
        stat_s[p][lt] = base80(&conv_s[p][0][0] + lt * 80);
    __syncthreads();
    if (lt == 0) {
        const float* s = stat_s[p];
        const float tot = fa(fa(fa(s[0],s[1]),fa(s[2],s[3])),
                             fa(fa(s[4],s[5]),fa(s[6],s[7])));
        mu_s[p] = __fdiv_rn(tot, 640.f);
    }
    __syncthreads();

    // ---- GN2 var
    if (lt < 8)
        stat_s[p][lt] = base80v(&conv_s[p][0][0] + lt * 80, mu_s[p]);
    __syncthreads();
    if (lt == 0) {
        const float* s = stat_s[p];
        const float tot = fa(fa(fa(s[0],s[1]),fa(s[2],s[3])),
                             fa(fa(s[4],s[5]),fa(s[6],s[7])));
        const float var = __fdiv_rn(tot, 640.f);
        rstd_s[p] = __fdiv_rn(1.f, __fsqrt_rn(fa(var, 1e-5f)));
    }
    __syncthreads();

    // ---- LIF2: 5 threads per pair (o = lt), spikes -> LDS
    if (lt < 5) {
        const int o = lt;
        const float mu = mu_s[p], rstd = rstd_s[p];
        const float gw = g2w[o], gb = g2b[o];
        float vm = 0.f;
        for (int t = 0; t < NT; ++t) {
            const float z  = conv_s[p][o][t];
            const float xn = fm(fs(z, mu), rstd);
            const float yn = fa(fm(xn, gw), gb);
            vm = fa(vm, fm(fs(yn, vm), 0.5f));
            const bool sp = (vm >= 0.8f);
            if (sp) vm = 0.f;
            const float so = sp ? 1.f : 0.f;
            spk_s[t][p * 10 + o]     = so;
            spk_s[t][p * 10 + 5 + o] = so;
        }
    }
    __syncthreads();

    // ---- coalesced store
    for (int q = tid; q < 1280; q += 512) {
        const int t = q / 10, s = q - t * 10;
        float4* dst = (float4*)(out + ((size_t)(t * NB + b) * 1280 + c0 * 10));
        dst[s] = reinterpret_cast<const float4*>(&spk_s[t][0])[s];
    }
}

// =========================================================================
extern "C" void kernel_launch(void* const* d_in, const int* in_sizes, int n_in,
                              void* d_out, int out_size, void* d_ws, size_t ws_size,
                              hipStream_t stream)
{
    const float* x   = (const float*)d_in[0];
    const float* W   = (const float*)d_in[1];
    const float* g1w = (const float*)d_in[2];
    const float* g1b = (const float*)d_in[3];
    const float* Wm  = (const float*)d_in[4];
    const float* g2w = (const float*)d_in[5];
    const float* g2b = (const float*)d_in[6];
    const float* adj = (const float*)d_in[7];
    float* out = (float*)d_out;

    float* y1 = (float*)d_ws;                                     // 41.9 MB
    ulonglong2* masks = (ulonglong2*)((char*)d_ws + (64u << 20)); // 1.3 MB
    float* Wt = (float*)((char*)d_ws + (80u << 20));              // 128 KB

    hipLaunchKernelGGL(kT, dim3(128), dim3(256), 0, stream, W, Wt);
    hipLaunchKernelGGL(kA, dim3(NT * NB / 8), dim3(256), 0, stream,
                       x, Wt, g1w, g1b, y1);
    hipLaunchKernelGGL(kB1, dim3(NB * 2), dim3(320), 0, stream,
                       y1, masks);
    hipLaunchKernelGGL(kB2, dim3(4096), dim3(512), 0, stream,
                       masks, Wm, g2w, g2b, adj, out);
}

// Round 21
// 179.352 us; speedup vs baseline: 1.3265x; 1.0484x over previous
//
#include <hip/hip_runtime.h>
#include <cstdint>
#include <cstddef>

#define NV 5
#define NC 128
#define NT 128
#define NB 128
typedef unsigned long long ull;
typedef float f32x2 __attribute__((ext_vector_type(2)));
typedef float f32x4 __attribute__((ext_vector_type(4)));

__device__ __forceinline__ float fa(float a, float b){ return __fadd_rn(a,b); }
__device__ __forceinline__ float fm(float a, float b){ return __fmul_rn(a,b); }
__device__ __forceinline__ float fs(float a, float b){ return __fsub_rn(a,b); }

// packed fp32: two independent IEEE-RNE ops per instruction (bit-identical
// to v_mul_f32/v_add_f32 per half)
__device__ __forceinline__ f32x2 pkadd(f32x2 a, f32x2 b){
    f32x2 d; asm("v_pk_add_f32 %0, %1, %2" : "=v"(d) : "v"(a), "v"(b)); return d;
}
// d = a * (w.lo, w.lo): src1 lo-half selected for both result halves.
__device__ __forceinline__ f32x2 pkmul_lo(f32x2 a, f32x2 w){
    f32x2 d; asm("v_pk_mul_f32 %0, %1, %2 op_sel:[0,0] op_sel_hi:[1,0]"
                 : "=v"(d) : "v"(a), "v"(w)); return d;
}
// d = a * (w.hi, w.hi): src1 hi-half selected for both result halves.
__device__ __forceinline__ f32x2 pkmul_hi(f32x2 a, f32x2 w){
    f32x2 d; asm("v_pk_mul_f32 %0, %1, %2 op_sel:[0,1] op_sel_hi:[1,1]"
                 : "=v"(d) : "v"(a), "v"(w)); return d;
}

// numpy pairwise_sum base case, n=80, contiguous fp32
__device__ __forceinline__ float base80(const float* a)
{
    float r0=a[0],r1=a[1],r2=a[2],r3=a[3],r4=a[4],r5=a[5],r6=a[6],r7=a[7];
    #pragma unroll
    for (int i = 8; i < 80; i += 8) {
        r0=fa(r0,a[i+0]); r1=fa(r1,a[i+1]); r2=fa(r2,a[i+2]); r3=fa(r3,a[i+3]);
        r4=fa(r4,a[i+4]); r5=fa(r5,a[i+5]); r6=fa(r6,a[i+6]); r7=fa(r7,a[i+7]);
    }
    return fa(fa(fa(r0,r1),fa(r2,r3)), fa(fa(r4,r5),fa(r6,r7)));
}

// base80 over (a[i]-mu)^2, identical op order to the var phase
__device__ __forceinline__ float base80v(const float* a, float mu)
{
    float r[8];
    #pragma unroll
    for (int j = 0; j < 8; ++j) { const float d = fs(a[j], mu); r[j] = fm(d, d); }
    #pragma unroll
    for (int i = 8; i < 80; i += 8)
        #pragma unroll
        for (int j = 0; j < 8; ++j) {
            const float d = fs(a[i + j], mu);
            r[j] = fa(r[j], fm(d, d));
        }
    return fa(fa(fa(r[0],r[1]),fa(r[2],r[3])), fa(fa(r[4],r[5]),fa(r[6],r[7])));
}

// =========================================================================
// Kernel T: W[o][c] -> Wt2[fc][oL] = (W[oL][fc], W[oL+64][fc]) pair.
// Same 128 KB total as the scalar table; kA loads both channel weights
// with ONE dwordx2 and consumes them via VOP3P op_sel (no pair-build movs).
// =========================================================================
__global__ __launch_bounds__(256) void kT(const float* __restrict__ W,
                                          f32x2* __restrict__ Wt2)
{
    const int i = blockIdx.x * 256 + threadIdx.x;   // 0..16383 = fc*64+oL
    const int fc = i >> 6, oL = i & 63;
    f32x2 p;
    p.x = W[oL * 256 + fc];
    p.y = W[(oL + 64) * 256 + fc];
    Wt2[i] = p;
}

// =========================================================================
// Kernel A: np-mimic fp32 fusion matmul + GN1 (R20 structure; W-pair +
// op_sel broadcast). 256 threads = 4 waves; wave wv owns samples
// {2wv,2wv+1}; thread owns channels {lane, lane+64}. LDS xs[fc][wv][v] =
// f32x2 (s0,s1) pairs. Per-output fp32 op sequence identical -> bit-exact.
// =========================================================================
__global__ __launch_bounds__(256) void kA(const float* __restrict__ x,
                                          const f32x2* __restrict__ Wt2,
                                          const float* __restrict__ g1w,
                                          const float* __restrict__ g1b,
                                          float* __restrict__ y1)
{
    const int n0   = blockIdx.x * 8;
    const int tid  = threadIdx.x;
    const int lane = tid & 63;
    const int wv   = tid >> 6;             // wave id == sample-pair id 0..3

    __shared__ __align__(16) float xs[256 * 4 * 12];   // 49152 B
    __shared__ float statA[8][4];
    __shared__ float muS[8], rstdS[8];

    // ---- stage: wave wv stages its samples {2wv, 2wv+1} as (s0,s1) pairs.
    // Wave-private region; same-wave DS ordering -> no barrier before matmul.
    {
        const float4* g0 = (const float4*)(x + (size_t)(n0 + 2 * wv) * 1280);
        const float4* g1 = g0 + 320;
        #pragma unroll
        for (int it = 0; it < 5; ++it) {
            const int k = it * 64 + lane;          // quad index 0..319
            const float4 a = g0[k];
            const float4 b = g1[k];
            const float av[4] = {a.x, a.y, a.z, a.w};
            const float bv[4] = {b.x, b.y, b.z, b.w};
            int f = k * 4;                          // flat idx in sample row
            #pragma unroll
            for (int e = 0; e < 4; ++e, ++f) {
                const int c  = f / 10;
                const int j  = f - c * 10;
                const int v  = (j < 5) ? j : j - 5;
                const int fc = (j < 5) ? c : c + 128;
                f32x2 pr; pr.x = av[e]; pr.y = bv[e];
                *(f32x2*)&xs[(fc * 4 + wv) * 12 + v * 2] = pr;  // b64
            }
        }
    }

    // ---- matmul: fc sequential 0..255 (acc half then gyr half); packed.
    // Each f32x2 half is an independent per-output chain -> bit-exact.
    f32x2 accA[NV], accB[NV];
    #pragma unroll
    for (int v = 0; v < NV; ++v) { accA[v] = (f32x2){0.f,0.f}; accB[v] = (f32x2){0.f,0.f}; }

    const float* xrow = xs + wv * 12;
    #pragma unroll 4
    for (int fc = 0; fc < 256; ++fc) {
        const f32x2 wab = Wt2[fc * 64 + lane];       // dwordx2, coalesced
        const f32x4 Q0 = *(const f32x4*)&xrow[fc * 48];       // v0,v1 pairs
        const f32x4 Q1 = *(const f32x4*)&xrow[fc * 48 + 4];   // v2,v3 pairs
        const f32x2 P4 = *(const f32x2*)&xrow[fc * 48 + 8];   // v4 pair
        const f32x2 p0 = __builtin_shufflevector(Q0, Q0, 0, 1);
        const f32x2 p1 = __builtin_shufflevector(Q0, Q0, 2, 3);
        const f32x2 p2 = __builtin_shufflevector(Q1, Q1, 0, 1);
        const f32x2 p3 = __builtin_shufflevector(Q1, Q1, 2, 3);
        accA[0] = pkadd(accA[0], pkmul_lo(p0, wab));
        accA[1] = pkadd(accA[1], pkmul_lo(p1, wab));
        accA[2] = pkadd(accA[2], pkmul_lo(p2, wab));
        accA[3] = pkadd(accA[3], pkmul_lo(p3, wab));
        accA[4] = pkadd(accA[4], pkmul_lo(P4, wab));
        accB[0] = pkadd(accB[0], pkmul_hi(p0, wab));
        accB[1] = pkadd(accB[1], pkmul_hi(p1, wab));
        accB[2] = pkadd(accB[2], pkmul_hi(p2, wab));
        accB[3] = pkadd(accB[3], pkmul_hi(p3, wab));
        accB[4] = pkadd(accB[4], pkmul_hi(P4, wab));
    }
    __syncthreads();   // other waves may still read xs; wait before ys reuse

    float* ys = xs;    // [8][640] = 5120 floats <= 12288 available ✓

    #pragma unroll
    for (int sl = 0; sl < 2; ++sl) {
        const int g = wv * 2 + sl;
        #pragma unroll
        for (int v = 0; v < NV; ++v) {
            ys[g * 640 + lane * 5 + v]        = sl ? accA[v].y : accA[v].x;
            ys[g * 640 + (lane + 64) * 5 + v] = sl ? accB[v].y : accB[v].x;
        }
    }
    __syncthreads();

    // mean: numpy pairwise over 640 (o-major order), 8 samples
    if (tid < 32) {
        const int g = tid >> 2, p = tid & 3;
        const float b0 = base80(&ys[g * 640 + (2 * p) * 80]);
        const float b1 = base80(&ys[g * 640 + (2 * p + 1) * 80]);
        statA[g][p] = fa(b0, b1);
    }
    __syncthreads();
    if (tid < 8) {
        const int g = tid;
        const float tot = fa(fa(statA[g][0], statA[g][1]), fa(statA[g][2], statA[g][3]));
        muS[g] = __fdiv_rn(tot, 640.f);
    }
    __syncthreads();

    // var: overwrite ys with (a - mu)^2, pairwise / 640
    #pragma unroll
    for (int sl = 0; sl < 2; ++sl) {
        const int g = wv * 2 + sl;
        const float mu = muS[g];
        #pragma unroll
        for (int v = 0; v < NV; ++v) {
            const float aA = sl ? accA[v].y : accA[v].x;
            const float aB = sl ? accB[v].y : accB[v].x;
            const float dA = fs(aA, mu);
            const float dB = fs(aB, mu);
            ys[g * 640 + lane * 5 + v]        = fm(dA, dA);
            ys[g * 640 + (lane + 64) * 5 + v] = fm(dB, dB);
        }
    }
    __syncthreads();
    if (tid < 32) {
        const int g = tid >> 2, p = tid & 3;
        const float b0 = base80(&ys[g * 640 + (2 * p) * 80]);
        const float b1 = base80(&ys[g * 640 + (2 * p + 1) * 80]);
        statA[g][p] = fa(b0, b1);
    }
    __syncthreads();
    if (tid < 8) {
        const int g = tid;
        const float tot = fa(fa(statA[g][0], statA[g][1]), fa(statA[g][2], statA[g][3]));
        const float var = __fdiv_rn(tot, 640.f);
        rstdS[g] = __fdiv_rn(1.f, __fsqrt_rn(fa(var, 1e-5f)));
    }
    __syncthreads();

    #pragma unroll
    for (int ch = 0; ch < 2; ++ch) {
        const int o = lane + ch * 64;
        const float wf = g1w[o], bf = g1b[o];
        #pragma unroll
        for (int sl = 0; sl < 2; ++sl) {
            const int g = wv * 2 + sl;
            const float mu = muS[g], rstd = rstdS[g];
            const int n = n0 + g;
            #pragma unroll
            for (int v = 0; v < NV; ++v) {
                const float av = ch ? (sl ? accB[v].y : accB[v].x)
                                    : (sl ? accA[v].y : accA[v].x);
                const float xn = fm(fs(av, mu), rstd);
                y1[(size_t)n * 640 + o * 5 + v] = fa(fm(xn, wf), bf);
            }
        }
    }
}

// =========================================================================
// Kernel B1: LIF1 (fp32, identical chain) -> ulonglong2 spike masks.
// =========================================================================
__global__ __launch_bounds__(320) void kB1(const float* __restrict__ y1,
                                           ulonglong2* __restrict__ masks)
{
    const int b   = blockIdx.x >> 1;
    const int c0  = (blockIdx.x & 1) * 64;
    const int tid = threadIdx.x;           // 0..319

    ull lo = 0ull, hi = 0ull;
    float vm = 0.f;
    const float* p = y1 + (size_t)b * 640 + (size_t)c0 * 5 + tid;
    for (int t0 = 0; t0 < NT; t0 += 16) {
        float xv[16];
        #pragma unroll
        for (int j = 0; j < 16; ++j)
            xv[j] = p[(size_t)(t0 + j) * (NB * 640)];
        #pragma unroll
        for (int j = 0; j < 16; ++j) {
            vm = fa(vm, fm(fs(xv[j], vm), 0.5f));
            if (vm >= 0.8f) {
                const int t = t0 + j;
                if (t < 64) lo |= 1ull << t; else hi |= 1ull << (t - 64);
                vm = 0.f;
            }
        }
    }
    masks[(size_t)b * 640 + (size_t)c0 * 5 + tid] = make_ulonglong2(lo, hi);
}

// =========================================================================
// Kernel B2: conv once (LDS) -> pairwise GN2 -> LIF2 -> coalesced stores.
// =========================================================================
__device__ __forceinline__ float bitf(ull lo, ull hi, int t)
{
    if (t < 0 || t > 127) return 0.f;
    return (float)(((t < 64) ? (lo >> t) : (hi >> (t - 64))) & 1ull);
}

__global__ __launch_bounds__(512) void kB2(const ulonglong2* __restrict__ masks,
                                           const float* __restrict__ Wm,
                                           const float* __restrict__ g2w,
                                           const float* __restrict__ g2b,
                                           const float* __restrict__ adj,
                                           float* __restrict__ out)
{
    const int blk = blockIdx.x;            // 0..4095
    const int b   = blk >> 5;              // 0..127
    const int c0  = (blk & 31) * 4;        // 0,4,..,124
    const int tid = threadIdx.x;           // 0..511
    const int p   = tid >> 7;              // pair 0..3
    const int lt  = tid & 127;             // t index / worker id

    __shared__ float mw_s[75];
    __shared__ ull   m_lo[4][5], m_hi[4][5];
    __shared__ float conv_s[4][5][128];
    __shared__ float spk_s[128][40];
    __shared__ float stat_s[4][8];
    __shared__ float mu_s[4], rstd_s[4];

    if (tid < 75) {
        const int oo = tid / 15, rem = tid % 15, ii = rem / 3;
        const float sym = fm(0.5f, fa(adj[oo * 5 + ii], adj[ii * 5 + oo]));
        const float e = (float)exp(-(double)sym);
        const float sig = __fdiv_rn(1.f, fa(1.f, e));
        mw_s[tid] = fm(Wm[tid], sig);
    }
    if (tid < 20) {
        const int pp = tid / 5, vv = tid % 5;
        const ulonglong2 m = masks[((size_t)b * 128 + c0 + pp) * 5 + vv];
        m_lo[pp][vv] = m.x; m_hi[pp][vv] = m.y;
    }
    __syncthreads();

    // ---- conv once: thread (p, t=lt); 15 shared bit extracts, 5 nodes
    {
        float bv[5][3];
        #pragma unroll
        for (int i = 0; i < 5; ++i) {
            const ull lo = m_lo[p][i], hi = m_hi[p][i];
            #pragma unroll
            for (int k = 0; k < 3; ++k)
                bv[i][k] = bitf(lo, hi, lt - 1 + k);
        }
        #pragma unroll
        for (int o = 0; o < 5; ++o) {
            float res = 0.f;
            #pragma unroll
            for (int i = 0; i < 5; ++i)
                #pragma unroll
                for (int k = 0; k < 3; ++k)
                    res = fa(res, fm(mw_s[(o * 5 + i) * 3 + k], bv[i][k]));
            conv_s[p][o][lt] = res;
        }
    }
    __syncthreads();

    // ---- GN2 mean
    if (lt < 8)
        stat_s[p][lt] = base80(&conv_s[p][0][0] + lt * 80);
    __syncthreads();
    if (lt == 0) {
        const float* s = stat_s[p];
        const float tot = fa(fa(fa(s[0],s[1]),fa(s[2],s[3])),
                             fa(fa(s[4],s[5]),fa(s[6],s[7])));
        mu_s[p] = __fdiv_rn(tot, 640.f);
    }
    __syncthreads();

    // ---- GN2 var
    if (lt < 8)
        stat_s[p][lt] = base80v(&conv_s[p][0][0] + lt * 80, mu_s[p]);
    __syncthreads();
    if (lt == 0) {
        const float* s = stat_s[p];
        const float tot = fa(fa(fa(s[0],s[1]),fa(s[2],s[3])),
                             fa(fa(s[4],s[5]),fa(s[6],s[7])));
        const float var = __fdiv_rn(tot, 640.f);
        rstd_s[p] = __fdiv_rn(1.f, __fsqrt_rn(fa(var, 1e-5f)));
    }
    __syncthreads();

    // ---- LIF2: 5 threads per pair (o = lt), spikes -> LDS
    if (lt < 5) {
        const int o = lt;
        const float mu = mu_s[p], rstd = rstd_s[p];
        const float gw = g2w[o], gb = g2b[o];
        float vm = 0.f;
        for (int t = 0; t < NT; ++t) {
            const float z  = conv_s[p][o][t];
            const float xn = fm(fs(z, mu), rstd);
            const float yn = fa(fm(xn, gw), gb);
            vm = fa(vm, fm(fs(yn, vm), 0.5f));
            const bool sp = (vm >= 0.8f);
            if (sp) vm = 0.f;
            const float so = sp ? 1.f : 0.f;
            spk_s[t][p * 10 + o]     = so;
            spk_s[t][p * 10 + 5 + o] = so;
        }
    }
    __syncthreads();

    // ---- coalesced store
    for (int q = tid; q < 1280; q += 512) {
        const int t = q / 10, s = q - t * 10;
        float4* dst = (float4*)(out + ((size_t)(t * NB + b) * 1280 + c0 * 10));
        dst[s] = reinterpret_cast<const float4*>(&spk_s[t][0])[s];
    }
}

// =========================================================================
extern "C" void kernel_launch(void* const* d_in, const int* in_sizes, int n_in,
                              void* d_out, int out_size, void* d_ws, size_t ws_size,
                              hipStream_t stream)
{
    const float* x   = (const float*)d_in[0];
    const float* W   = (const float*)d_in[1];
    const float* g1w = (const float*)d_in[2];
    const float* g1b = (const float*)d_in[3];
    const float* Wm  = (const float*)d_in[4];
    const float* g2w = (const float*)d_in[5];
    const float* g2b = (const float*)d_in[6];
    const float* adj = (const float*)d_in[7];
    float* out = (float*)d_out;

    float* y1 = (float*)d_ws;                                     // 41.9 MB
    ulonglong2* masks = (ulonglong2*)((char*)d_ws + (64u << 20)); // 1.3 MB
    f32x2* Wt2 = (f32x2*)((char*)d_ws + (80u << 20));             // 128 KB

    hipLaunchKernelGGL(kT, dim3(64), dim3(256), 0, stream, W, Wt2);
    hipLaunchKernelGGL(kA, dim3(NT * NB / 8), dim3(256), 0, stream,
                       x, Wt2, g1w, g1b, y1);
    hipLaunchKernelGGL(kB1, dim3(NB * 2), dim3(320), 0, stream,
                       y1, masks);
    hipLaunchKernelGGL(kB2, dim3(4096), dim3(512), 0, stream,
                       masks, Wm, g2w, g2b, adj, out);
}